// Round 7
// baseline (1669.469 us; speedup 1.0000x reference)
//
#include <hip/hip_runtime.h>

#define N_INST 200000
#define N_NET  50000
#define NTOT   250000
#define NE     2000000
#define DD     64
#define OUTSTRIDE 256   // (L+1)*D

#define SCAN_CHUNK 1024
#define NSCAN_BLOCKS ((NTOT + SCAN_CHUNK - 1) / SCAN_CHUNK)   // 245

// partitioned CSR fill: 16 dst-ranges; per-XCD live set ~2.1MB of 4MB L2
#define NPART 16
#define PART_SZ (NTOT/NPART)      // 15625
#define ECHUNK 8000
#define NCHUNK (NE/ECHUNK)        // 250

__device__ __forceinline__ float leaky(float x){ return x > 0.f ? x : 0.1f*x; }

// ---------------- encoders ----------------

__global__ __launch_bounds__(256) void encode_inst(
    const float* __restrict__ x, const float* __restrict__ W1, const float* __restrict__ b1,
    const float* __restrict__ W2, const float* __restrict__ b2, float* __restrict__ out)
{
  __shared__ float sW1t[128*16];    // transposed: [k][i] so column k is 4x float4
  __shared__ float sW2[128*64];
  __shared__ float sb1[128];
  __shared__ float sb2[64];
  for (int i = threadIdx.x; i < 16*128; i += 256){
    int row = i >> 7, k = i & 127;
    sW1t[k*16 + row] = W1[i];       // one-time transpose (bank conflicts OK, staging only)
  }
  for (int i = threadIdx.x; i < 128*64; i += 256) sW2[i] = W2[i];
  if (threadIdx.x < 128) sb1[threadIdx.x] = b1[threadIdx.x];
  if (threadIdx.x < 64)  sb2[threadIdx.x] = b2[threadIdx.x];
  __syncthreads();
  int n = blockIdx.x*256 + threadIdx.x;
  if (n >= N_INST) return;
  float4 xv[4];
  #pragma unroll
  for (int i=0;i<4;i++) xv[i] = ((const float4*)(x + (size_t)n*16))[i];
  float4 acc[16];
  #pragma unroll
  for (int q=0;q<16;q++) acc[q] = ((const float4*)sb2)[q];
  for (int k=0;k<128;k++){
    const float4* w1 = (const float4*)(sW1t + k*16);
    float4 a0=w1[0], a1=w1[1], a2=w1[2], a3=w1[3];
    float t = sb1[k]
      + xv[0].x*a0.x + xv[0].y*a0.y + xv[0].z*a0.z + xv[0].w*a0.w
      + xv[1].x*a1.x + xv[1].y*a1.y + xv[1].z*a1.z + xv[1].w*a1.w
      + xv[2].x*a2.x + xv[2].y*a2.y + xv[2].z*a2.z + xv[2].w*a2.w
      + xv[3].x*a3.x + xv[3].y*a3.y + xv[3].z*a3.z + xv[3].w*a3.w;
    t = leaky(t);
    const float4* w2 = (const float4*)(sW2 + k*64);
    #pragma unroll
    for (int q=0;q<16;q++){
      float4 w = w2[q];
      acc[q].x += t*w.x; acc[q].y += t*w.y; acc[q].z += t*w.z; acc[q].w += t*w.w;
    }
  }
  float4* o4 = (float4*)(out + (size_t)n*OUTSTRIDE);
  #pragma unroll
  for (int q=0;q<16;q++)
    o4[q] = make_float4(leaky(acc[q].x), leaky(acc[q].y), leaky(acc[q].z), leaky(acc[q].w));
}

__global__ __launch_bounds__(256) void encode_net(
    const float* __restrict__ x, const float* __restrict__ W1, const float* __restrict__ b1,
    const float* __restrict__ W2, const float* __restrict__ b2, float* __restrict__ out)
{
  __shared__ float sW1t[64*8];      // transposed: [k][i]
  __shared__ float sW2[64*64];
  __shared__ float sb1[64];
  __shared__ float sb2[64];
  for (int i = threadIdx.x; i < 8*64; i += 256){
    int row = i >> 6, k = i & 63;
    sW1t[k*8 + row] = W1[i];
  }
  for (int i = threadIdx.x; i < 64*64; i += 256) sW2[i] = W2[i];
  if (threadIdx.x < 64){ sb1[threadIdx.x] = b1[threadIdx.x]; sb2[threadIdx.x] = b2[threadIdx.x]; }
  __syncthreads();
  int n = blockIdx.x*256 + threadIdx.x;
  if (n >= N_NET) return;
  float4 xv[2];
  #pragma unroll
  for (int i=0;i<2;i++) xv[i] = ((const float4*)(x + (size_t)n*8))[i];
  float4 acc[16];
  #pragma unroll
  for (int q=0;q<16;q++) acc[q] = ((const float4*)sb2)[q];
  for (int k=0;k<64;k++){
    const float4* w1 = (const float4*)(sW1t + k*8);
    float4 a0=w1[0], a1=w1[1];
    float t = sb1[k]
      + xv[0].x*a0.x + xv[0].y*a0.y + xv[0].z*a0.z + xv[0].w*a0.w
      + xv[1].x*a1.x + xv[1].y*a1.y + xv[1].z*a1.z + xv[1].w*a1.w;
    t = leaky(t);
    const float4* w2 = (const float4*)(sW2 + k*64);
    #pragma unroll
    for (int q=0;q<16;q++){
      float4 w = w2[q];
      acc[q].x += t*w.x; acc[q].y += t*w.y; acc[q].z += t*w.z; acc[q].w += t*w.w;
    }
  }
  float4* o4 = (float4*)(out + (size_t)(N_INST + n)*OUTSTRIDE);
  #pragma unroll
  for (int q=0;q<16;q++)
    o4[q] = make_float4(leaky(acc[q].x), leaky(acc[q].y), leaky(acc[q].z), leaky(acc[q].w));
}

// ---------------- degrees ----------------

__global__ void count_deg(const int* __restrict__ ei, unsigned* __restrict__ cf, unsigned* __restrict__ cr)
{
  int e = blockIdx.x*256 + threadIdx.x;
  if (e < NE){
    atomicAdd(&cf[ei[e]], 1u);       // hist(row) -> deg_f, rev-CSR counts
    atomicAdd(&cr[ei[NE+e]], 1u);    // hist(col) -> deg_r, fwd-CSR counts
  }
}

__global__ void compute_dis(const unsigned* __restrict__ cf, const unsigned* __restrict__ cr,
                            float* __restrict__ dis_f, float* __restrict__ dis_r,
                            float* __restrict__ idf, float* __restrict__ idr)
{
  int n = blockIdx.x*256 + threadIdx.x;
  if (n < NTOT){
    float df = (float)cf[n] + 1.0f;
    float dr = (float)cr[n] + 1.0f;
    dis_f[n] = rsqrtf(df); idf[n] = 1.0f/df;
    dis_r[n] = rsqrtf(dr); idr[n] = 1.0f/dr;
  }
}

// ---------------- exclusive scan (3 stages, 2 arrays via gridDim.y) ----------------

__global__ __launch_bounds__(256) void scan_stage1(
    const unsigned* __restrict__ in0, unsigned* __restrict__ out0, unsigned* __restrict__ sums0,
    const unsigned* __restrict__ in1, unsigned* __restrict__ out1, unsigned* __restrict__ sums1)
{
  const unsigned* in  = blockIdx.y ? in1  : in0;
  unsigned* out  = blockIdx.y ? out1  : out0;
  unsigned* sums = blockIdx.y ? sums1 : sums0;
  __shared__ unsigned lds[256];
  int base = blockIdx.x * SCAN_CHUNK + threadIdx.x*4;
  unsigned v[4];
  #pragma unroll
  for (int i=0;i<4;i++){ int idx = base+i; v[i] = (idx < NTOT) ? in[idx] : 0u; }
  unsigned tsum = v[0]+v[1]+v[2]+v[3];
  lds[threadIdx.x] = tsum;
  __syncthreads();
  for (int ofs=1; ofs<256; ofs<<=1){
    unsigned t = (threadIdx.x >= (unsigned)ofs) ? lds[threadIdx.x-ofs] : 0u;
    __syncthreads();
    lds[threadIdx.x] += t;
    __syncthreads();
  }
  unsigned run = lds[threadIdx.x] - tsum;   // exclusive within chunk
  #pragma unroll
  for (int i=0;i<4;i++){ int idx = base+i; if (idx < NTOT) out[idx] = run; run += v[i]; }
  if (threadIdx.x == 255) sums[blockIdx.x] = lds[255];
}

__global__ __launch_bounds__(256) void scan_stage2(
    unsigned* __restrict__ sums0, unsigned* __restrict__ ptr0,
    unsigned* __restrict__ sums1, unsigned* __restrict__ ptr1)
{
  unsigned* sums = blockIdx.y ? sums1 : sums0;
  unsigned* ptr  = blockIdx.y ? ptr1  : ptr0;
  __shared__ unsigned lds[256];
  unsigned v = (threadIdx.x < NSCAN_BLOCKS) ? sums[threadIdx.x] : 0u;
  lds[threadIdx.x] = v;
  __syncthreads();
  for (int ofs=1; ofs<256; ofs<<=1){
    unsigned t = (threadIdx.x >= (unsigned)ofs) ? lds[threadIdx.x-ofs] : 0u;
    __syncthreads();
    lds[threadIdx.x] += t;
    __syncthreads();
  }
  if (threadIdx.x < NSCAN_BLOCKS) sums[threadIdx.x] = lds[threadIdx.x] - v;  // exclusive
  if (threadIdx.x == 255) ptr[NTOT] = lds[255];                              // = NE
}

__global__ __launch_bounds__(256) void scan_stage3(
    unsigned* __restrict__ out0, const unsigned* __restrict__ sums0,
    unsigned* __restrict__ out1, const unsigned* __restrict__ sums1)
{
  unsigned* out = blockIdx.y ? out1 : out0;
  unsigned add  = (blockIdx.y ? sums1 : sums0)[blockIdx.x];
  int base = blockIdx.x*SCAN_CHUNK + threadIdx.x;
  #pragma unroll
  for (int i=0;i<4;i++){ int idx = base + i*256; if (idx < NTOT) out[idx] += add; }
}

// ---------------- partitioned CSR fill (src-only payload, nt edge loads) ----
// blockIdx.x = chunk*NPART + part; round-robin dispatch keeps each partition's
// ~2.1MB CSR slice on one XCD L2. Edge stream uses non-temporal loads so it
// does not evict CSR lines (fix for the r4->r6 eviction failure).

__global__ __launch_bounds__(256) void fill_csr_part(
    const int* __restrict__ ei,
    unsigned* __restrict__ curf, unsigned* __restrict__ curr,
    unsigned* __restrict__ csrf, unsigned* __restrict__ csrr)
{
  const int part  = blockIdx.x & (NPART-1);
  const int chunk = blockIdx.x / NPART;
  const int lo = part * PART_SZ;
  const int hi = lo + PART_SZ;
  const int e0 = chunk * ECHUNK;
  for (int e = e0 + threadIdx.x; e < e0 + ECHUNK; e += 256){
    int r = __builtin_nontemporal_load(ei + e);
    int c = __builtin_nontemporal_load(ei + NE + e);
    if (c >= lo && c < hi){                      // fwd: grouped by destination col
      unsigned pf = atomicAdd(&curf[c], 1u);
      csrf[pf] = (unsigned)r;
    }
    if (r >= lo && r < hi){                      // rev: grouped by destination row
      unsigned pr = atomicAdd(&curr[r], 1u);
      csrr[pr] = (unsigned)c;
    }
  }
}

// ---------------- per-layer linear: register-cached weights ----------------

__global__ __launch_bounds__(256, 2) void layer_linear(
    const float* __restrict__ hin,   // row stride OUTSTRIDE
    const float* __restrict__ Wf, const float* __restrict__ bf, const float* __restrict__ rootf,
    const float* __restrict__ Wr, const float* __restrict__ br, const float* __restrict__ rootr,
    const float* __restrict__ idf, const float* __restrict__ idr,
    float* __restrict__ rxf, float* __restrict__ rxr, float* __restrict__ self)
{
  __shared__ float4 sh[128*16];     // [node][f4]  32 KB
  const int tid = threadIdx.x;
  const int j   = tid & 63;
  const int wv  = tid >> 6;
  const int base = blockIdx.x * 128;

  #pragma unroll
  for (int i = 0; i < 8; ++i){
    int idx = tid + i*256;
    int gn = base + (idx >> 4);
    float4 v = make_float4(0.f,0.f,0.f,0.f);
    if (gn < NTOT) v = ((const float4*)(hin + (size_t)gn*OUTSTRIDE))[idx & 15];
    sh[idx] = v;
  }

  float wf[64], wr[64];
  #pragma unroll
  for (int k=0;k<64;k++){ wf[k] = Wf[k*64+j]; wr[k] = Wr[k*64+j]; }
  const float bfv = bf[j], brv = br[j], rfv = rootf[j], rrv = rootr[j];
  __syncthreads();

  #pragma unroll 2
  for (int t = 0; t < 32; ++t){
    int ln = wv*32 + t;
    int gn = base + ln;
    float af = bfv, ar = brv;
    #pragma unroll
    for (int k4 = 0; k4 < 16; ++k4){
      float4 h = sh[ln*16 + k4];
      af += h.x*wf[4*k4] + h.y*wf[4*k4+1] + h.z*wf[4*k4+2] + h.w*wf[4*k4+3];
      ar += h.x*wr[4*k4] + h.y*wr[4*k4+1] + h.z*wr[4*k4+2] + h.w*wr[4*k4+3];
    }
    if (gn < NTOT){
      size_t o = (size_t)gn*DD + j;
      rxf[o] = fmaxf(af, 0.f);
      rxr[o] = fmaxf(ar, 0.f);
      self[o] = fmaxf(af + rfv, 0.f)*idf[gn] + fmaxf(ar + rrv, 0.f)*idr[gn];
    }
  }
}

// ---------------- fused CSR aggregation (fwd+rev) + LayerNorm + leaky ----------------
// norm recomputed from cache-resident dis tables: dis[src]*dis[n] (bit-identical
// to the old precomputed product).

__global__ __launch_bounds__(256) void aggregate_ln(
    const unsigned* __restrict__ ptrf, const unsigned* __restrict__ csrf,
    const unsigned* __restrict__ ptrr, const unsigned* __restrict__ csrr,
    const float* __restrict__ dis_f, const float* __restrict__ dis_r,
    const float* __restrict__ rxf, const float* __restrict__ rxr,
    const float* __restrict__ self,
    const float* __restrict__ g, const float* __restrict__ b,
    float* __restrict__ out)    // already offset by (l+1)*DD
{
  int grp  = threadIdx.x >> 4;
  int lane = threadIdx.x & 15;
  int n = blockIdx.x*16 + grp;

  float4 acc = ((const float4*)(self + (size_t)n*DD))[lane];

  #pragma unroll
  for (int dir = 0; dir < 2; ++dir){
    const unsigned* ptr = dir ? ptrr : ptrf;
    const unsigned* csr = dir ? csrr : csrf;
    const float*    dis = dir ? dis_r : dis_f;
    const float*    rx  = dir ? rxr  : rxf;
    const float     disn = dis[n];
    unsigned p0 = ptr[n], p1 = ptr[n+1];
    while (p0 < p1){
      unsigned take = p1 - p0; if (take > 16u) take = 16u;
      unsigned src_l = (lane < (int)take) ? csr[p0 + lane] : 0u;
      float    val_l = (lane < (int)take) ? dis[src_l]*disn : 0.f;
      unsigned take4 = (take + 3u) & ~3u;      // padded lanes have val 0
      for (unsigned jj = 0; jj < take4; jj += 4){
        int   s0 = __shfl((int)src_l, (int)jj+0, 16), s1 = __shfl((int)src_l, (int)jj+1, 16);
        int   s2 = __shfl((int)src_l, (int)jj+2, 16), s3 = __shfl((int)src_l, (int)jj+3, 16);
        float v0 = __shfl(val_l, (int)jj+0, 16), v1 = __shfl(val_l, (int)jj+1, 16);
        float v2 = __shfl(val_l, (int)jj+2, 16), v3 = __shfl(val_l, (int)jj+3, 16);
        float4 r0 = ((const float4*)(rx + (size_t)s0*DD))[lane];
        float4 r1 = ((const float4*)(rx + (size_t)s1*DD))[lane];
        float4 r2 = ((const float4*)(rx + (size_t)s2*DD))[lane];
        float4 r3 = ((const float4*)(rx + (size_t)s3*DD))[lane];
        acc.x += v0*r0.x + v1*r1.x + v2*r2.x + v3*r3.x;
        acc.y += v0*r0.y + v1*r1.y + v2*r2.y + v3*r3.y;
        acc.z += v0*r0.z + v1*r1.z + v2*r2.z + v3*r3.z;
        acc.w += v0*r0.w + v1*r1.w + v2*r2.w + v3*r3.w;
      }
      p0 += take;
    }
  }

  float s1 = acc.x + acc.y + acc.z + acc.w;
  #pragma unroll
  for (int m=1;m<16;m<<=1) s1 += __shfl_xor(s1, m, 16);
  float mean = s1 * (1.f/64.f);
  float dx = acc.x-mean, dy = acc.y-mean, dz = acc.z-mean, dw = acc.w-mean;
  float q = dx*dx + dy*dy + dz*dz + dw*dw;
  #pragma unroll
  for (int m=1;m<16;m<<=1) q += __shfl_xor(q, m, 16);
  float inv = rsqrtf(q*(1.f/64.f) + 1e-5f);
  float4 g4 = ((const float4*)g)[lane];
  float4 b4 = ((const float4*)b)[lane];
  float4 y;
  y.x = leaky(dx*inv*g4.x + b4.x);
  y.y = leaky(dy*inv*g4.y + b4.y);
  y.z = leaky(dz*inv*g4.z + b4.z);
  y.w = leaky(dw*inv*g4.w + b4.w);
  ((float4*)(out + (size_t)n*OUTSTRIDE))[lane] = y;
}

// ---------------- launch ----------------

extern "C" void kernel_launch(void* const* d_in, const int* in_sizes, int n_in,
                              void* d_out, int out_size, void* d_ws, size_t ws_size,
                              hipStream_t stream)
{
  const float* x       = (const float*)d_in[0];
  const float* x_net   = (const float*)d_in[1];
  const int*   ei      = (const int*)  d_in[2];
  const float* enc1_W  = (const float*)d_in[3];
  const float* enc1_b  = (const float*)d_in[4];
  const float* enc2_W  = (const float*)d_in[5];
  const float* enc2_b  = (const float*)d_in[6];
  const float* net1_W  = (const float*)d_in[7];
  const float* net1_b  = (const float*)d_in[8];
  const float* net2_W  = (const float*)d_in[9];
  const float* net2_b  = (const float*)d_in[10];
  const float* conv_W  = (const float*)d_in[11];
  const float* conv_b  = (const float*)d_in[12];
  const float* conv_rt = (const float*)d_in[13];
  const float* re_W    = (const float*)d_in[14];
  const float* re_b    = (const float*)d_in[15];
  const float* re_rt   = (const float*)d_in[16];
  const float* ln_g    = (const float*)d_in[17];
  const float* ln_b    = (const float*)d_in[18];
  float* out = (float*)d_out;

  char* ws = (char*)d_ws;
  size_t off = 0;
  const size_t NDB = (size_t)NTOT*DD*sizeof(float);   // 64 MB
  float* rxf    = (float*)(ws + off); off += NDB;
  float* rxr    = (float*)(ws + off); off += NDB;
  float* self   = (float*)(ws + off); off += NDB;
  unsigned* csrf= (unsigned*)(ws + off); off += (size_t)NE*4;
  unsigned* csrr= (unsigned*)(ws + off); off += (size_t)NE*4;
  float* dis_f  = (float*)(ws + off); off += (size_t)NTOT*4;
  float* dis_r  = (float*)(ws + off); off += (size_t)NTOT*4;
  float* idf    = (float*)(ws + off); off += (size_t)NTOT*4;
  float* idr    = (float*)(ws + off); off += (size_t)NTOT*4;
  unsigned* cf  = (unsigned*)(ws + off); off += (size_t)NTOT*4;   // cf,cr contiguous (one memset)
  unsigned* cr  = (unsigned*)(ws + off); off += (size_t)NTOT*4;
  unsigned* ptrf= (unsigned*)(ws + off); off += (size_t)(NTOT+1)*4 + 4;
  unsigned* ptrr= (unsigned*)(ws + off); off += (size_t)(NTOT+1)*4 + 4;
  unsigned* curf= (unsigned*)(ws + off); off += (size_t)NTOT*4;
  unsigned* curr= (unsigned*)(ws + off); off += (size_t)NTOT*4;
  unsigned* sums0=(unsigned*)(ws + off); off += 4096;
  unsigned* sums1=(unsigned*)(ws + off); off += 4096;

  hipMemsetAsync(cf, 0, (size_t)NTOT*4*2, stream);

  count_deg<<<(NE+255)/256, 256, 0, stream>>>(ei, cf, cr);
  compute_dis<<<(NTOT+255)/256, 256, 0, stream>>>(cf, cr, dis_f, dis_r, idf, idr);

  // ptrf = exclusive_scan(cr)  (fwd CSR grouped by col)
  // ptrr = exclusive_scan(cf)  (rev CSR grouped by row)
  scan_stage1<<<dim3(NSCAN_BLOCKS,2), 256, 0, stream>>>(cr, ptrf, sums0, cf, ptrr, sums1);
  scan_stage2<<<dim3(1,2),            256, 0, stream>>>(sums0, ptrf, sums1, ptrr);
  scan_stage3<<<dim3(NSCAN_BLOCKS,2), 256, 0, stream>>>(ptrf, sums0, ptrr, sums1);

  hipMemcpyAsync(curf, ptrf, (size_t)NTOT*4, hipMemcpyDeviceToDevice, stream);
  hipMemcpyAsync(curr, ptrr, (size_t)NTOT*4, hipMemcpyDeviceToDevice, stream);
  fill_csr_part<<<NCHUNK*NPART, 256, 0, stream>>>(ei, curf, curr, csrf, csrr);

  encode_inst<<<(N_INST+255)/256, 256, 0, stream>>>(x, enc1_W, enc1_b, enc2_W, enc2_b, out);
  encode_net <<<(N_NET +255)/256, 256, 0, stream>>>(x_net, net1_W, net1_b, net2_W, net2_b, out);

  for (int l=0; l<3; ++l){
    layer_linear<<<(NTOT+127)/128, 256, 0, stream>>>(out + l*DD,
        conv_W + (size_t)l*DD*DD, conv_b + l*DD, conv_rt + l*DD,
        re_W   + (size_t)l*DD*DD, re_b   + l*DD, re_rt   + l*DD,
        idf, idr, rxf, rxr, self);
    aggregate_ln<<<NTOT/16, 256, 0, stream>>>(ptrf, csrf, ptrr, csrr,
        dis_f, dis_r, rxf, rxr, self, ln_g + l*DD, ln_b + l*DD, out + (l+1)*DD);
  }
}

// Round 8
// 1347.555 us; speedup vs baseline: 1.2389x; 1.2389x over previous
//
#include <hip/hip_runtime.h>

#define N_INST 200000
#define N_NET  50000
#define NTOT   250000
#define NE     2000000
#define DD     64
#define OUTSTRIDE 256   // (L+1)*D

#define SCAN_CHUNK 1024
#define NSCAN_BLOCKS ((NTOT + SCAN_CHUNK - 1) / SCAN_CHUNK)   // 245

// partitioned CSR fill (round-6 best config)
#define NPART 8
#define PART_SZ (NTOT/NPART)
#define ECHUNK 8000
#define NCHUNK (NE/ECHUNK)        // 250

__device__ __forceinline__ float leaky(float x){ return x > 0.f ? x : 0.1f*x; }

// f32 -> bf16 (round-to-nearest-even), and back. rx values are post-relu finite >= 0.
__device__ __forceinline__ unsigned short f2bf(float f){
  unsigned u = __float_as_uint(f);
  return (unsigned short)((u + 0x7FFFu + ((u >> 16) & 1u)) >> 16);
}
__device__ __forceinline__ float bf2f(unsigned short h){
  return __uint_as_float((unsigned)h << 16);
}

// ---------------- encoders ----------------

__global__ __launch_bounds__(256) void encode_inst(
    const float* __restrict__ x, const float* __restrict__ W1, const float* __restrict__ b1,
    const float* __restrict__ W2, const float* __restrict__ b2, float* __restrict__ out)
{
  __shared__ float sW1t[128*16];    // transposed: [k][i] so column k is 4x float4
  __shared__ float sW2[128*64];
  __shared__ float sb1[128];
  __shared__ float sb2[64];
  for (int i = threadIdx.x; i < 16*128; i += 256){
    int row = i >> 7, k = i & 127;
    sW1t[k*16 + row] = W1[i];
  }
  for (int i = threadIdx.x; i < 128*64; i += 256) sW2[i] = W2[i];
  if (threadIdx.x < 128) sb1[threadIdx.x] = b1[threadIdx.x];
  if (threadIdx.x < 64)  sb2[threadIdx.x] = b2[threadIdx.x];
  __syncthreads();
  int n = blockIdx.x*256 + threadIdx.x;
  if (n >= N_INST) return;
  float4 xv[4];
  #pragma unroll
  for (int i=0;i<4;i++) xv[i] = ((const float4*)(x + (size_t)n*16))[i];
  float4 acc[16];
  #pragma unroll
  for (int q=0;q<16;q++) acc[q] = ((const float4*)sb2)[q];
  for (int k=0;k<128;k++){
    const float4* w1 = (const float4*)(sW1t + k*16);
    float4 a0=w1[0], a1=w1[1], a2=w1[2], a3=w1[3];
    float t = sb1[k]
      + xv[0].x*a0.x + xv[0].y*a0.y + xv[0].z*a0.z + xv[0].w*a0.w
      + xv[1].x*a1.x + xv[1].y*a1.y + xv[1].z*a1.z + xv[1].w*a1.w
      + xv[2].x*a2.x + xv[2].y*a2.y + xv[2].z*a2.z + xv[2].w*a2.w
      + xv[3].x*a3.x + xv[3].y*a3.y + xv[3].z*a3.z + xv[3].w*a3.w;
    t = leaky(t);
    const float4* w2 = (const float4*)(sW2 + k*64);
    #pragma unroll
    for (int q=0;q<16;q++){
      float4 w = w2[q];
      acc[q].x += t*w.x; acc[q].y += t*w.y; acc[q].z += t*w.z; acc[q].w += t*w.w;
    }
  }
  float4* o4 = (float4*)(out + (size_t)n*OUTSTRIDE);
  #pragma unroll
  for (int q=0;q<16;q++)
    o4[q] = make_float4(leaky(acc[q].x), leaky(acc[q].y), leaky(acc[q].z), leaky(acc[q].w));
}

__global__ __launch_bounds__(256) void encode_net(
    const float* __restrict__ x, const float* __restrict__ W1, const float* __restrict__ b1,
    const float* __restrict__ W2, const float* __restrict__ b2, float* __restrict__ out)
{
  __shared__ float sW1t[64*8];      // transposed: [k][i]
  __shared__ float sW2[64*64];
  __shared__ float sb1[64];
  __shared__ float sb2[64];
  for (int i = threadIdx.x; i < 8*64; i += 256){
    int row = i >> 6, k = i & 63;
    sW1t[k*8 + row] = W1[i];
  }
  for (int i = threadIdx.x; i < 64*64; i += 256) sW2[i] = W2[i];
  if (threadIdx.x < 64){ sb1[threadIdx.x] = b1[threadIdx.x]; sb2[threadIdx.x] = b2[threadIdx.x]; }
  __syncthreads();
  int n = blockIdx.x*256 + threadIdx.x;
  if (n >= N_NET) return;
  float4 xv[2];
  #pragma unroll
  for (int i=0;i<2;i++) xv[i] = ((const float4*)(x + (size_t)n*8))[i];
  float4 acc[16];
  #pragma unroll
  for (int q=0;q<16;q++) acc[q] = ((const float4*)sb2)[q];
  for (int k=0;k<64;k++){
    const float4* w1 = (const float4*)(sW1t + k*8);
    float4 a0=w1[0], a1=w1[1];
    float t = sb1[k]
      + xv[0].x*a0.x + xv[0].y*a0.y + xv[0].z*a0.z + xv[0].w*a0.w
      + xv[1].x*a1.x + xv[1].y*a1.y + xv[1].z*a1.z + xv[1].w*a1.w;
    t = leaky(t);
    const float4* w2 = (const float4*)(sW2 + k*64);
    #pragma unroll
    for (int q=0;q<16;q++){
      float4 w = w2[q];
      acc[q].x += t*w.x; acc[q].y += t*w.y; acc[q].z += t*w.z; acc[q].w += t*w.w;
    }
  }
  float4* o4 = (float4*)(out + (size_t)(N_INST + n)*OUTSTRIDE);
  #pragma unroll
  for (int q=0;q<16;q++)
    o4[q] = make_float4(leaky(acc[q].x), leaky(acc[q].y), leaky(acc[q].z), leaky(acc[q].w));
}

// ---------------- degrees ----------------

__global__ void count_deg(const int* __restrict__ ei, unsigned* __restrict__ cf, unsigned* __restrict__ cr)
{
  int e = blockIdx.x*256 + threadIdx.x;
  if (e < NE){
    atomicAdd(&cf[ei[e]], 1u);       // hist(row) -> deg_f, rev-CSR counts
    atomicAdd(&cr[ei[NE+e]], 1u);    // hist(col) -> deg_r, fwd-CSR counts
  }
}

__global__ void compute_dis(const unsigned* __restrict__ cf, const unsigned* __restrict__ cr,
                            float* __restrict__ dis_f, float* __restrict__ dis_r,
                            float* __restrict__ idf, float* __restrict__ idr)
{
  int n = blockIdx.x*256 + threadIdx.x;
  if (n < NTOT){
    float df = (float)cf[n] + 1.0f;
    float dr = (float)cr[n] + 1.0f;
    dis_f[n] = rsqrtf(df); idf[n] = 1.0f/df;
    dis_r[n] = rsqrtf(dr); idr[n] = 1.0f/dr;
  }
}

// ---------------- exclusive scan (3 stages, 2 arrays via gridDim.y) ----------------

__global__ __launch_bounds__(256) void scan_stage1(
    const unsigned* __restrict__ in0, unsigned* __restrict__ out0, unsigned* __restrict__ sums0,
    const unsigned* __restrict__ in1, unsigned* __restrict__ out1, unsigned* __restrict__ sums1)
{
  const unsigned* in  = blockIdx.y ? in1  : in0;
  unsigned* out  = blockIdx.y ? out1  : out0;
  unsigned* sums = blockIdx.y ? sums1 : sums0;
  __shared__ unsigned lds[256];
  int base = blockIdx.x * SCAN_CHUNK + threadIdx.x*4;
  unsigned v[4];
  #pragma unroll
  for (int i=0;i<4;i++){ int idx = base+i; v[i] = (idx < NTOT) ? in[idx] : 0u; }
  unsigned tsum = v[0]+v[1]+v[2]+v[3];
  lds[threadIdx.x] = tsum;
  __syncthreads();
  for (int ofs=1; ofs<256; ofs<<=1){
    unsigned t = (threadIdx.x >= (unsigned)ofs) ? lds[threadIdx.x-ofs] : 0u;
    __syncthreads();
    lds[threadIdx.x] += t;
    __syncthreads();
  }
  unsigned run = lds[threadIdx.x] - tsum;   // exclusive within chunk
  #pragma unroll
  for (int i=0;i<4;i++){ int idx = base+i; if (idx < NTOT) out[idx] = run; run += v[i]; }
  if (threadIdx.x == 255) sums[blockIdx.x] = lds[255];
}

__global__ __launch_bounds__(256) void scan_stage2(
    unsigned* __restrict__ sums0, unsigned* __restrict__ ptr0,
    unsigned* __restrict__ sums1, unsigned* __restrict__ ptr1)
{
  unsigned* sums = blockIdx.y ? sums1 : sums0;
  unsigned* ptr  = blockIdx.y ? ptr1  : ptr0;
  __shared__ unsigned lds[256];
  unsigned v = (threadIdx.x < NSCAN_BLOCKS) ? sums[threadIdx.x] : 0u;
  lds[threadIdx.x] = v;
  __syncthreads();
  for (int ofs=1; ofs<256; ofs<<=1){
    unsigned t = (threadIdx.x >= (unsigned)ofs) ? lds[threadIdx.x-ofs] : 0u;
    __syncthreads();
    lds[threadIdx.x] += t;
    __syncthreads();
  }
  if (threadIdx.x < NSCAN_BLOCKS) sums[threadIdx.x] = lds[threadIdx.x] - v;  // exclusive
  if (threadIdx.x == 255) ptr[NTOT] = lds[255];                              // = NE
}

// stage3 also seeds the fill cursors (folds the old 2x hipMemcpyAsync)
__global__ __launch_bounds__(256) void scan_stage3(
    unsigned* __restrict__ out0, const unsigned* __restrict__ sums0, unsigned* __restrict__ cur0,
    unsigned* __restrict__ out1, const unsigned* __restrict__ sums1, unsigned* __restrict__ cur1)
{
  unsigned* out = blockIdx.y ? out1 : out0;
  unsigned* cur = blockIdx.y ? cur1 : cur0;
  unsigned add  = (blockIdx.y ? sums1 : sums0)[blockIdx.x];
  int base = blockIdx.x*SCAN_CHUNK + threadIdx.x;
  #pragma unroll
  for (int i=0;i<4;i++){
    int idx = base + i*256;
    if (idx < NTOT){ unsigned v = out[idx] + add; out[idx] = v; cur[idx] = v; }
  }
}

// ---------------- partitioned CSR fill (round-6 config: uint2, NPART=8) ----

__global__ __launch_bounds__(256) void fill_csr_part(
    const int* __restrict__ ei,
    const float* __restrict__ dis_f, const float* __restrict__ dis_r,
    unsigned* __restrict__ curf, unsigned* __restrict__ curr,
    uint2* __restrict__ csrf, uint2* __restrict__ csrr)
{
  const int part  = blockIdx.x & (NPART-1);
  const int chunk = blockIdx.x / NPART;
  const int lo = part * PART_SZ;
  const int hi = lo + PART_SZ;
  const int e0 = chunk * ECHUNK;
  for (int e = e0 + threadIdx.x; e < e0 + ECHUNK; e += 256){
    int r = ei[e], c = ei[NE+e];
    if (c >= lo && c < hi){                      // fwd: grouped by destination col
      float nf = dis_f[r]*dis_f[c];
      unsigned pf = atomicAdd(&curf[c], 1u);
      csrf[pf] = make_uint2((unsigned)r, __float_as_uint(nf));
    }
    if (r >= lo && r < hi){                      // rev: grouped by destination row
      float nr = dis_r[r]*dis_r[c];
      unsigned pr = atomicAdd(&curr[r], 1u);
      csrr[pr] = make_uint2((unsigned)c, __float_as_uint(nr));
    }
  }
}

// ---------------- per-layer linear: register-cached weights, bf16 rx out ----

__global__ __launch_bounds__(256, 2) void layer_linear(
    const float* __restrict__ hin,   // row stride OUTSTRIDE
    const float* __restrict__ Wf, const float* __restrict__ bf, const float* __restrict__ rootf,
    const float* __restrict__ Wr, const float* __restrict__ br, const float* __restrict__ rootr,
    const float* __restrict__ idf, const float* __restrict__ idr,
    unsigned short* __restrict__ rxf, unsigned short* __restrict__ rxr,
    float* __restrict__ self)
{
  __shared__ float4 sh[128*16];     // [node][f4]  32 KB
  const int tid = threadIdx.x;
  const int j   = tid & 63;
  const int wv  = tid >> 6;
  const int base = blockIdx.x * 128;

  #pragma unroll
  for (int i = 0; i < 8; ++i){
    int idx = tid + i*256;
    int gn = base + (idx >> 4);
    float4 v = make_float4(0.f,0.f,0.f,0.f);
    if (gn < NTOT) v = ((const float4*)(hin + (size_t)gn*OUTSTRIDE))[idx & 15];
    sh[idx] = v;
  }

  float wf[64], wr[64];
  #pragma unroll
  for (int k=0;k<64;k++){ wf[k] = Wf[k*64+j]; wr[k] = Wr[k*64+j]; }
  const float bfv = bf[j], brv = br[j], rfv = rootf[j], rrv = rootr[j];
  __syncthreads();

  #pragma unroll 2
  for (int t = 0; t < 32; ++t){
    int ln = wv*32 + t;
    int gn = base + ln;
    float af = bfv, ar = brv;
    #pragma unroll
    for (int k4 = 0; k4 < 16; ++k4){
      float4 h = sh[ln*16 + k4];
      af += h.x*wf[4*k4] + h.y*wf[4*k4+1] + h.z*wf[4*k4+2] + h.w*wf[4*k4+3];
      ar += h.x*wr[4*k4] + h.y*wr[4*k4+1] + h.z*wr[4*k4+2] + h.w*wr[4*k4+3];
    }
    if (gn < NTOT){
      size_t o = (size_t)gn*DD + j;
      rxf[o] = f2bf(fmaxf(af, 0.f));
      rxr[o] = f2bf(fmaxf(ar, 0.f));
      self[o] = fmaxf(af + rfv, 0.f)*idf[gn] + fmaxf(ar + rrv, 0.f)*idr[gn];
    }
  }
}

// ---------------- fused CSR aggregation (fwd+rev, bf16 gathers) + LN + leaky --

__global__ __launch_bounds__(256) void aggregate_ln(
    const unsigned* __restrict__ ptrf, const uint2* __restrict__ csrf,
    const unsigned* __restrict__ ptrr, const uint2* __restrict__ csrr,
    const unsigned short* __restrict__ rxf, const unsigned short* __restrict__ rxr,
    const float* __restrict__ self,
    const float* __restrict__ g, const float* __restrict__ b,
    float* __restrict__ out)    // already offset by (l+1)*DD
{
  int grp  = threadIdx.x >> 4;
  int lane = threadIdx.x & 15;
  int n = blockIdx.x*16 + grp;

  float4 acc = ((const float4*)(self + (size_t)n*DD))[lane];

  #pragma unroll
  for (int dir = 0; dir < 2; ++dir){
    const unsigned* ptr = dir ? ptrr : ptrf;
    const uint2*    csr = dir ? csrr : csrf;
    const unsigned short* rx = dir ? rxr : rxf;
    unsigned p0 = ptr[n], p1 = ptr[n+1];
    while (p0 < p1){
      unsigned take = p1 - p0; if (take > 16u) take = 16u;
      uint2 ev = (lane < (int)take) ? csr[p0 + lane] : make_uint2(0u, 0u);
      int   src_l = (int)ev.x;
      float val_l = __uint_as_float(ev.y);
      unsigned take4 = (take + 3u) & ~3u;      // padded lanes have val 0
      for (unsigned jj = 0; jj < take4; jj += 4){
        int   s0 = __shfl(src_l, (int)jj+0, 16), s1 = __shfl(src_l, (int)jj+1, 16);
        int   s2 = __shfl(src_l, (int)jj+2, 16), s3 = __shfl(src_l, (int)jj+3, 16);
        float v0 = __shfl(val_l, (int)jj+0, 16), v1 = __shfl(val_l, (int)jj+1, 16);
        float v2 = __shfl(val_l, (int)jj+2, 16), v3 = __shfl(val_l, (int)jj+3, 16);
        ushort4 q0 = ((const ushort4*)(rx + (size_t)s0*DD))[lane];
        ushort4 q1 = ((const ushort4*)(rx + (size_t)s1*DD))[lane];
        ushort4 q2 = ((const ushort4*)(rx + (size_t)s2*DD))[lane];
        ushort4 q3 = ((const ushort4*)(rx + (size_t)s3*DD))[lane];
        acc.x += v0*bf2f(q0.x) + v1*bf2f(q1.x) + v2*bf2f(q2.x) + v3*bf2f(q3.x);
        acc.y += v0*bf2f(q0.y) + v1*bf2f(q1.y) + v2*bf2f(q2.y) + v3*bf2f(q3.y);
        acc.z += v0*bf2f(q0.z) + v1*bf2f(q1.z) + v2*bf2f(q2.z) + v3*bf2f(q3.z);
        acc.w += v0*bf2f(q0.w) + v1*bf2f(q1.w) + v2*bf2f(q2.w) + v3*bf2f(q3.w);
      }
      p0 += take;
    }
  }

  float s1 = acc.x + acc.y + acc.z + acc.w;
  #pragma unroll
  for (int m=1;m<16;m<<=1) s1 += __shfl_xor(s1, m, 16);
  float mean = s1 * (1.f/64.f);
  float dx = acc.x-mean, dy = acc.y-mean, dz = acc.z-mean, dw = acc.w-mean;
  float q = dx*dx + dy*dy + dz*dz + dw*dw;
  #pragma unroll
  for (int m=1;m<16;m<<=1) q += __shfl_xor(q, m, 16);
  float inv = rsqrtf(q*(1.f/64.f) + 1e-5f);
  float4 g4 = ((const float4*)g)[lane];
  float4 b4 = ((const float4*)b)[lane];
  float4 y;
  y.x = leaky(dx*inv*g4.x + b4.x);
  y.y = leaky(dy*inv*g4.y + b4.y);
  y.z = leaky(dz*inv*g4.z + b4.z);
  y.w = leaky(dw*inv*g4.w + b4.w);
  ((float4*)(out + (size_t)n*OUTSTRIDE))[lane] = y;
}

// ---------------- launch ----------------

extern "C" void kernel_launch(void* const* d_in, const int* in_sizes, int n_in,
                              void* d_out, int out_size, void* d_ws, size_t ws_size,
                              hipStream_t stream)
{
  const float* x       = (const float*)d_in[0];
  const float* x_net   = (const float*)d_in[1];
  const int*   ei      = (const int*)  d_in[2];
  const float* enc1_W  = (const float*)d_in[3];
  const float* enc1_b  = (const float*)d_in[4];
  const float* enc2_W  = (const float*)d_in[5];
  const float* enc2_b  = (const float*)d_in[6];
  const float* net1_W  = (const float*)d_in[7];
  const float* net1_b  = (const float*)d_in[8];
  const float* net2_W  = (const float*)d_in[9];
  const float* net2_b  = (const float*)d_in[10];
  const float* conv_W  = (const float*)d_in[11];
  const float* conv_b  = (const float*)d_in[12];
  const float* conv_rt = (const float*)d_in[13];
  const float* re_W    = (const float*)d_in[14];
  const float* re_b    = (const float*)d_in[15];
  const float* re_rt   = (const float*)d_in[16];
  const float* ln_g    = (const float*)d_in[17];
  const float* ln_b    = (const float*)d_in[18];
  float* out = (float*)d_out;

  char* ws = (char*)d_ws;
  size_t off = 0;
  unsigned short* rxf = (unsigned short*)(ws + off); off += (size_t)NTOT*DD*2;  // 32 MB
  unsigned short* rxr = (unsigned short*)(ws + off); off += (size_t)NTOT*DD*2;  // 32 MB
  float* self   = (float*)(ws + off); off += (size_t)NTOT*DD*4;                 // 64 MB
  uint2* csrf   = (uint2*)(ws + off); off += (size_t)NE*8;
  uint2* csrr   = (uint2*)(ws + off); off += (size_t)NE*8;
  float* dis_f  = (float*)(ws + off); off += (size_t)NTOT*4;
  float* dis_r  = (float*)(ws + off); off += (size_t)NTOT*4;
  float* idf    = (float*)(ws + off); off += (size_t)NTOT*4;
  float* idr    = (float*)(ws + off); off += (size_t)NTOT*4;
  unsigned* cf  = (unsigned*)(ws + off); off += (size_t)NTOT*4;   // cf,cr contiguous (one memset)
  unsigned* cr  = (unsigned*)(ws + off); off += (size_t)NTOT*4;
  unsigned* ptrf= (unsigned*)(ws + off); off += (size_t)(NTOT+1)*4 + 4;
  unsigned* ptrr= (unsigned*)(ws + off); off += (size_t)(NTOT+1)*4 + 4;
  unsigned* curf= (unsigned*)(ws + off); off += (size_t)NTOT*4;
  unsigned* curr= (unsigned*)(ws + off); off += (size_t)NTOT*4;
  unsigned* sums0=(unsigned*)(ws + off); off += 4096;
  unsigned* sums1=(unsigned*)(ws + off); off += 4096;

  hipMemsetAsync(cf, 0, (size_t)NTOT*4*2, stream);

  count_deg<<<(NE+255)/256, 256, 0, stream>>>(ei, cf, cr);
  compute_dis<<<(NTOT+255)/256, 256, 0, stream>>>(cf, cr, dis_f, dis_r, idf, idr);

  // ptrf = exclusive_scan(cr)  (fwd CSR grouped by col)
  // ptrr = exclusive_scan(cf)  (rev CSR grouped by row)
  scan_stage1<<<dim3(NSCAN_BLOCKS,2), 256, 0, stream>>>(cr, ptrf, sums0, cf, ptrr, sums1);
  scan_stage2<<<dim3(1,2),            256, 0, stream>>>(sums0, ptrf, sums1, ptrr);
  scan_stage3<<<dim3(NSCAN_BLOCKS,2), 256, 0, stream>>>(ptrf, sums0, curf, ptrr, sums1, curr);

  fill_csr_part<<<NCHUNK*NPART, 256, 0, stream>>>(ei, dis_f, dis_r, curf, curr, csrf, csrr);

  encode_inst<<<(N_INST+255)/256, 256, 0, stream>>>(x, enc1_W, enc1_b, enc2_W, enc2_b, out);
  encode_net <<<(N_NET +255)/256, 256, 0, stream>>>(x_net, net1_W, net1_b, net2_W, net2_b, out);

  for (int l=0; l<3; ++l){
    layer_linear<<<(NTOT+127)/128, 256, 0, stream>>>(out + l*DD,
        conv_W + (size_t)l*DD*DD, conv_b + l*DD, conv_rt + l*DD,
        re_W   + (size_t)l*DD*DD, re_b   + l*DD, re_rt   + l*DD,
        idf, idr, rxf, rxr, self);
    aggregate_ln<<<NTOT/16, 256, 0, stream>>>(ptrf, csrf, ptrr, csrr,
        rxf, rxr, self, ln_g + l*DD, ln_b + l*DD, out + (l+1)*DD);
  }
}